// Round 1
// baseline (1123.194 us; speedup 1.0000x reference)
//
#include <hip/hip_runtime.h>
#include <hip/hip_bf16.h>

// Llama4 MoE: T=1024 tokens, H=2048 hidden, I=4096 intermediate, E=8 experts, top-1.
// Strategy: fp32 router -> token gather per expert -> grouped bf16-MFMA GEMMs
// (shared + 8 experts), weights converted fp32->bf16 during LDS staging with an
// in-register transpose (8 coalesced n-major loads -> 1 ds_write_b128 per k-row).

constexpr int Tn = 1024;
constexpr int Hn = 2048;
constexpr int In = 4096;

typedef __attribute__((ext_vector_type(8))) short bf16x8;
typedef __attribute__((ext_vector_type(4))) float f32x4;

__device__ inline unsigned short f2bf(float f) {
  unsigned u = __float_as_uint(f);
  unsigned r = (u + 0x7fffu + ((u >> 16) & 1u)) >> 16;  // RNE
  return (unsigned short)r;
}

union U4 { unsigned short us[8]; uint4 v; };

// ---------------- init: zero the atomic counters ----------------
__global__ void init_kernel(int* cnt) {
  if (threadIdx.x < 8) cnt[threadIdx.x] = 0;
}

// ---------------- router: logits = x @ w_router, top-1 + sigmoid ----------------
__global__ void router_kernel(const float* __restrict__ x, const float* __restrict__ wr,
                              int* __restrict__ eid, float* __restrict__ score,
                              int* __restrict__ cnt) {
  int wave = threadIdx.x >> 6, lane = threadIdx.x & 63;
  int t = blockIdx.x * 4 + wave;
  float acc[8];
#pragma unroll
  for (int e = 0; e < 8; ++e) acc[e] = 0.f;
  const float* xr = x + (size_t)t * Hn;
  for (int h = lane; h < Hn; h += 64) {
    float xv = xr[h];
    float4 w0 = *(const float4*)(wr + (size_t)h * 8);
    float4 w1 = *(const float4*)(wr + (size_t)h * 8 + 4);
    acc[0] += xv * w0.x; acc[1] += xv * w0.y; acc[2] += xv * w0.z; acc[3] += xv * w0.w;
    acc[4] += xv * w1.x; acc[5] += xv * w1.y; acc[6] += xv * w1.z; acc[7] += xv * w1.w;
  }
#pragma unroll
  for (int e = 0; e < 8; ++e) {
#pragma unroll
    for (int off = 32; off; off >>= 1) acc[e] += __shfl_down(acc[e], off);
  }
  if (lane == 0) {
    int be = 0; float bv = acc[0];
#pragma unroll
    for (int e = 1; e < 8; ++e) { if (acc[e] > bv) { bv = acc[e]; be = e; } }
    eid[t] = be;
    score[t] = 1.f / (1.f + __expf(-bv));
    atomicAdd(&cnt[be], 1);
  }
}

// ---------------- scan + row assignment (single block) ----------------
__global__ void scan_assign_kernel(const int* __restrict__ eid, const int* __restrict__ cnt,
                                   int* __restrict__ off, int* __restrict__ t2r) {
  __shared__ int s_off[8];
  __shared__ int s_cur[8];
  if (threadIdx.x == 0) {
    int run = 0;
    for (int e = 0; e < 8; ++e) { s_off[e] = run; off[e] = run; run += cnt[e]; }
  }
  if (threadIdx.x < 8) s_cur[threadIdx.x] = 0;
  __syncthreads();
  for (int t = threadIdx.x; t < Tn; t += 256) {
    int e = eid[t];
    int r = atomicAdd(&s_cur[e], 1);
    t2r[t] = s_off[e] + r;
  }
}

// ---------------- x prep: X_all rows [0,1024)=x bf16, [1024,2048)=permuted scaled ----------------
__global__ void xprep_kernel(const float* __restrict__ x, const float* __restrict__ score,
                             const int* __restrict__ t2r, unsigned short* __restrict__ Xall) {
  int t = blockIdx.x;
  int c = threadIdx.x * 8;
  const float4 a = *(const float4*)(x + (size_t)t * Hn + c);
  const float4 b = *(const float4*)(x + (size_t)t * Hn + c + 4);
  float s = score[t];
  int r = t2r[t];
  U4 p;
  p.us[0] = f2bf(a.x); p.us[1] = f2bf(a.y); p.us[2] = f2bf(a.z); p.us[3] = f2bf(a.w);
  p.us[4] = f2bf(b.x); p.us[5] = f2bf(b.y); p.us[6] = f2bf(b.z); p.us[7] = f2bf(b.w);
  *(uint4*)&Xall[(size_t)t * Hn + c] = p.v;
  p.us[0] = f2bf(a.x * s); p.us[1] = f2bf(a.y * s); p.us[2] = f2bf(a.z * s); p.us[3] = f2bf(a.w * s);
  p.us[4] = f2bf(b.x * s); p.us[5] = f2bf(b.y * s); p.us[6] = f2bf(b.z * s); p.us[7] = f2bf(b.w * s);
  *(uint4*)&Xall[(size_t)(Tn + r) * Hn + c] = p.v;
}

// ---------------- fused gate+up grouped GEMM -> H_all = silu(g)*u (bf16) ----------------
// Tile: BM=128, BN=128, BK=32. 4 waves in 2x2, each 64x64 via 4x4 of 16x16x32 MFMA.
__global__ __launch_bounds__(256, 2) void gateup_kernel(
    const unsigned short* __restrict__ Xall,
    const float* __restrict__ wsg, const float* __restrict__ wsu,
    const float* __restrict__ weg, const float* __restrict__ weu,
    const int* __restrict__ cnt, const int* __restrict__ off,
    unsigned short* __restrict__ Hall) {
  __shared__ __align__(16) unsigned short As[128 * 40];
  __shared__ __align__(16) unsigned short Bsg[128 * 40];
  __shared__ __align__(16) unsigned short Bsu[128 * 40];

  const int n0 = blockIdx.x * 128;
  const int gy = blockIdx.y;
  int row0, valid;
  const float *Bg, *Bu;
  if (gy < 8) {
    row0 = gy * 128; valid = 128; Bg = wsg; Bu = wsu;
  } else {
    int g = (gy - 8) >> 3, mt = (gy - 8) & 7;
    int c = cnt[g];
    if (mt * 128 >= c) return;
    row0 = Tn + off[g] + mt * 128;
    valid = c - mt * 128; if (valid > 128) valid = 128;
    Bg = weg + (size_t)g * Hn * In;
    Bu = weu + (size_t)g * Hn * In;
  }
  const int tid = threadIdx.x;
  const int wv = tid >> 6, lane = tid & 63;
  const int wm = (wv >> 1) * 64, wn = (wv & 1) * 64;
  const int lr = lane & 15, q = lane >> 4;

  f32x4 accg[4][4], accu[4][4];
#pragma unroll
  for (int i = 0; i < 4; ++i)
#pragma unroll
    for (int j = 0; j < 4; ++j) { accg[i][j] = (f32x4)0.f; accu[i][j] = (f32x4)0.f; }

  // A staging: thread covers rows (tid>>2) and (tid>>2)+64, k-chunk (tid&3)*8
  const int a_row = tid >> 2, a_c = tid & 3;
  int ar0 = row0 + a_row;        if (a_row >= valid) ar0 = row0;
  int ar1 = row0 + a_row + 64;   if (a_row + 64 >= valid) ar1 = row0;
  const unsigned short* ap0 = Xall + (size_t)ar0 * Hn + a_c * 8;
  const unsigned short* ap1 = Xall + (size_t)ar1 * Hn + a_c * 8;
  // B staging: lane covers n = n0 + 2*lane (+1); wave covers k-octet wv
  const float* bgp = Bg + (size_t)(wv * 8) * In + n0 + 2 * lane;
  const float* bup = Bu + (size_t)(wv * 8) * In + n0 + 2 * lane;

  for (int k0 = 0; k0 < Hn; k0 += 32) {
    uint4 av0 = *(const uint4*)ap0;
    uint4 av1 = *(const uint4*)ap1;
    U4 pg0, pg1, pu0, pu1;
#pragma unroll
    for (int j = 0; j < 8; ++j) {
      float2 vg = *(const float2*)(bgp + (size_t)j * In);
      float2 vu = *(const float2*)(bup + (size_t)j * In);
      pg0.us[j] = f2bf(vg.x); pg1.us[j] = f2bf(vg.y);
      pu0.us[j] = f2bf(vu.x); pu1.us[j] = f2bf(vu.y);
    }
    __syncthreads();
    *(uint4*)&As[a_row * 40 + a_c * 8] = av0;
    *(uint4*)&As[(a_row + 64) * 40 + a_c * 8] = av1;
    *(uint4*)&Bsg[(2 * lane) * 40 + wv * 8] = pg0.v;
    *(uint4*)&Bsg[(2 * lane + 1) * 40 + wv * 8] = pg1.v;
    *(uint4*)&Bsu[(2 * lane) * 40 + wv * 8] = pu0.v;
    *(uint4*)&Bsu[(2 * lane + 1) * 40 + wv * 8] = pu1.v;
    __syncthreads();

    bf16x8 af[4], bgf[4], buf[4];
#pragma unroll
    for (int i = 0; i < 4; ++i) {
      af[i]  = *(const bf16x8*)&As[(wm + i * 16 + lr) * 40 + q * 8];
      bgf[i] = *(const bf16x8*)&Bsg[(wn + i * 16 + lr) * 40 + q * 8];
      buf[i] = *(const bf16x8*)&Bsu[(wn + i * 16 + lr) * 40 + q * 8];
    }
#pragma unroll
    for (int mi = 0; mi < 4; ++mi)
#pragma unroll
      for (int ni = 0; ni < 4; ++ni) {
        accg[mi][ni] = __builtin_amdgcn_mfma_f32_16x16x32_bf16(af[mi], bgf[ni], accg[mi][ni], 0, 0, 0);
        accu[mi][ni] = __builtin_amdgcn_mfma_f32_16x16x32_bf16(af[mi], buf[ni], accu[mi][ni], 0, 0, 0);
      }
    ap0 += 32; ap1 += 32;
    bgp += (size_t)32 * In; bup += (size_t)32 * In;
  }

  // epilogue: h = silu(g) * u -> bf16
#pragma unroll
  for (int mi = 0; mi < 4; ++mi) {
#pragma unroll
    for (int r = 0; r < 4; ++r) {
      int m = wm + mi * 16 + q * 4 + r;
      if (m < valid) {
        size_t rowbase = (size_t)(row0 + m) * In + n0;
#pragma unroll
        for (int ni = 0; ni < 4; ++ni) {
          float g = accg[mi][ni][r];
          float u = accu[mi][ni][r];
          float hv = g / (1.f + __expf(-g)) * u;
          Hall[rowbase + wn + ni * 16 + lr] = f2bf(hv);
        }
      }
    }
  }
}

// ---------------- down grouped GEMM -> D_all fp32 ----------------
// Tile: BM=128, BN=64, BK=32. 4 waves 2x2, each 64x32 (4x2 frags).
__global__ __launch_bounds__(256, 3) void down_kernel(
    const unsigned short* __restrict__ Hall,
    const float* __restrict__ wsd, const float* __restrict__ wed,
    const int* __restrict__ cnt, const int* __restrict__ off,
    float* __restrict__ Dall) {
  __shared__ __align__(16) unsigned short As[128 * 40];
  __shared__ __align__(16) unsigned short Bs[64 * 40];

  const int n0 = blockIdx.x * 64;
  const int gy = blockIdx.y;
  int row0, valid;
  const float* Bsrc;
  if (gy < 8) {
    row0 = gy * 128; valid = 128; Bsrc = wsd;
  } else {
    int g = (gy - 8) >> 3, mt = (gy - 8) & 7;
    int c = cnt[g];
    if (mt * 128 >= c) return;
    row0 = Tn + off[g] + mt * 128;
    valid = c - mt * 128; if (valid > 128) valid = 128;
    Bsrc = wed + (size_t)g * In * Hn;
  }
  const int tid = threadIdx.x;
  const int wv = tid >> 6, lane = tid & 63;
  const int wm = (wv >> 1) * 64, wn = (wv & 1) * 32;
  const int lr = lane & 15, q = lane >> 4;

  f32x4 acc[4][2];
#pragma unroll
  for (int i = 0; i < 4; ++i) { acc[i][0] = (f32x4)0.f; acc[i][1] = (f32x4)0.f; }

  const int a_row = tid >> 2, a_c = tid & 3;
  int ar0 = row0 + a_row;        if (a_row >= valid) ar0 = row0;
  int ar1 = row0 + a_row + 64;   if (a_row + 64 >= valid) ar1 = row0;
  const unsigned short* ap0 = Hall + (size_t)ar0 * In + a_c * 8;
  const unsigned short* ap1 = Hall + (size_t)ar1 * In + a_c * 8;
  const float* bp = Bsrc + (size_t)(wv * 8) * Hn + n0 + lane;  // n = n0+lane, k-octet wv

  for (int k0 = 0; k0 < In; k0 += 32) {
    uint4 av0 = *(const uint4*)ap0;
    uint4 av1 = *(const uint4*)ap1;
    U4 pb;
#pragma unroll
    for (int j = 0; j < 8; ++j) pb.us[j] = f2bf(bp[(size_t)j * Hn]);
    __syncthreads();
    *(uint4*)&As[a_row * 40 + a_c * 8] = av0;
    *(uint4*)&As[(a_row + 64) * 40 + a_c * 8] = av1;
    *(uint4*)&Bs[lane * 40 + wv * 8] = pb.v;
    __syncthreads();

    bf16x8 af[4], bf[2];
#pragma unroll
    for (int i = 0; i < 4; ++i) af[i] = *(const bf16x8*)&As[(wm + i * 16 + lr) * 40 + q * 8];
#pragma unroll
    for (int i = 0; i < 2; ++i) bf[i] = *(const bf16x8*)&Bs[(wn + i * 16 + lr) * 40 + q * 8];
#pragma unroll
    for (int mi = 0; mi < 4; ++mi)
#pragma unroll
      for (int ni = 0; ni < 2; ++ni)
        acc[mi][ni] = __builtin_amdgcn_mfma_f32_16x16x32_bf16(af[mi], bf[ni], acc[mi][ni], 0, 0, 0);
    ap0 += 32; ap1 += 32;
    bp += (size_t)32 * Hn;
  }

#pragma unroll
  for (int mi = 0; mi < 4; ++mi) {
#pragma unroll
    for (int r = 0; r < 4; ++r) {
      int m = wm + mi * 16 + q * 4 + r;
      if (m < valid) {
        size_t rowbase = (size_t)(row0 + m) * Hn + n0;
#pragma unroll
        for (int ni = 0; ni < 2; ++ni)
          Dall[rowbase + wn + ni * 16 + lr] = acc[mi][ni][r];
      }
    }
  }
}

// ---------------- combine: out[t] = D_sh[t] + D_rt[t2r[t]] ----------------
__global__ void combine_kernel(const float* __restrict__ Dall, const int* __restrict__ t2r,
                               float* __restrict__ out) {
  int t = blockIdx.x;
  int r = t2r[t];
  int c = threadIdx.x * 8;
  const float4 a0 = *(const float4*)(Dall + (size_t)t * Hn + c);
  const float4 a1 = *(const float4*)(Dall + (size_t)t * Hn + c + 4);
  const float4 b0 = *(const float4*)(Dall + (size_t)(Tn + r) * Hn + c);
  const float4 b1 = *(const float4*)(Dall + (size_t)(Tn + r) * Hn + c + 4);
  float4 o0, o1;
  o0.x = a0.x + b0.x; o0.y = a0.y + b0.y; o0.z = a0.z + b0.z; o0.w = a0.w + b0.w;
  o1.x = a1.x + b1.x; o1.y = a1.y + b1.y; o1.z = a1.z + b1.z; o1.w = a1.w + b1.w;
  *(float4*)(out + (size_t)t * Hn + c) = o0;
  *(float4*)(out + (size_t)t * Hn + c + 4) = o1;
}

extern "C" void kernel_launch(void* const* d_in, const int* in_sizes, int n_in,
                              void* d_out, int out_size, void* d_ws, size_t ws_size,
                              hipStream_t stream) {
  const float* x   = (const float*)d_in[0];
  const float* wr  = (const float*)d_in[1];
  const float* wsg = (const float*)d_in[2];
  const float* wsu = (const float*)d_in[3];
  const float* wsd = (const float*)d_in[4];
  const float* weg = (const float*)d_in[5];
  const float* weu = (const float*)d_in[6];
  const float* wed = (const float*)d_in[7];
  float* out = (float*)d_out;

  char* ws = (char*)d_ws;
  unsigned short* Xall = (unsigned short*)(ws);                 // 2048*2048*2  = 8 MB
  unsigned short* Hall = (unsigned short*)(ws + 8388608);       // 2048*4096*2  = 16 MB
  float*          Dall = (float*)(ws + 25165824);               // 2048*2048*4  = 16 MB
  float*          score = (float*)(ws + 41943040);
  int*            eid   = (int*)(ws + 41947136);
  int*            t2r   = (int*)(ws + 41951232);
  int*            cnt   = (int*)(ws + 41955328);
  int*            off   = (int*)(ws + 41955360);

  init_kernel<<<1, 64, 0, stream>>>(cnt);
  router_kernel<<<256, 256, 0, stream>>>(x, wr, eid, score, cnt);
  scan_assign_kernel<<<1, 256, 0, stream>>>(eid, cnt, off, t2r);
  xprep_kernel<<<Tn, 256, 0, stream>>>(x, score, t2r, Xall);
  gateup_kernel<<<dim3(32, 72), 256, 0, stream>>>(Xall, wsg, wsu, weg, weu, cnt, off, Hall);
  down_kernel<<<dim3(32, 72), 256, 0, stream>>>(Hall, wsd, wed, cnt, off, Dall);
  combine_kernel<<<Tn, 256, 0, stream>>>(Dall, t2r, out);
}